// Round 8
// baseline (293.376 us; speedup 1.0000x reference)
//
#include <hip/hip_runtime.h>
#include <hip/hip_cooperative_groups.h>
#include <math.h>

namespace cg = cooperative_groups;

// ---------------------------------------------------------------------------
// ConvLogicNetCIFAR forward. R8: ONE cooperative kernel, 256 blocks x 1024
// threads (1 block/CU -> all 256 CUs busy; R7's 128-block mega idled half the
// chip at VALUBusy 16%). Activations live in GLOBAL memory (L2-resident),
// feature-major [feat][bpair=64] h2 layout: every load/store is a coalesced
// 256B segment, NO LDS activations -> no bank conflicts (R7: 4.2M conflict
// cycles). grid.sync() between stages replaces ~10us/dispatch graph-node gaps.
// Phases: P0 prep(softmax coefs + FC tree chase)+binarize | conv1..4 | FC
// (block LDS tree-reduce -> part, no atomics) | final class reduce.
// Gate: c0 + c1*a + c2*b + c3*(a*b), c = softmax(w_row)@COEF.
// Conv tree quirk: off=2^lvl-1 -> level0 rows0..3, level1 rows1..2, level2 row3.
// ---------------------------------------------------------------------------

typedef _Float16 h2 __attribute__((ext_vector_type(2)));

#define GSZ (256 * 1024)

__constant__ float c_coef_tbl[16][4] = {
    {0, 0, 0, 0}, {0, 0, 0, 1}, {0, 1, 0, -1}, {0, 1, 0, 0},
    {0, 0, 1, -1}, {0, 0, 1, 0}, {0, 1, 1, -2}, {0, 1, 1, -1},
    {1, -1, -1, 1}, {1, -1, -1, 2}, {1, 0, -1, 0}, {1, 0, -1, 1},
    {1, -1, 0, 0}, {1, -1, 0, 1}, {1, 0, 0, -1}, {1, 0, 0, 0}};

__device__ __forceinline__ float4 softmax_coef(const float* __restrict__ wr) {
  float m = -1e30f;
#pragma unroll
  for (int k = 0; k < 16; ++k) m = fmaxf(m, wr[k]);
  float e[16], s = 0.f;
#pragma unroll
  for (int k = 0; k < 16; ++k) { e[k] = __expf(wr[k] - m); s += e[k]; }
  float inv = 1.f / s;
  float c0 = 0.f, c1 = 0.f, c2 = 0.f, c3 = 0.f;
#pragma unroll
  for (int k = 0; k < 16; ++k) {
    c0 += e[k] * c_coef_tbl[k][0];
    c1 += e[k] * c_coef_tbl[k][1];
    c2 += e[k] * c_coef_tbl[k][2];
    c3 += e[k] * c_coef_tbl[k][3];
  }
  return make_float4(c0 * inv, c1 * inv, c2 * inv, c3 * inv);
}

__device__ __forceinline__ float2 gate2(float4 c, float2 a, float2 b) {
  float2 r;
  r.x = c.x + c.y * a.x + c.z * b.x + c.w * (a.x * b.x);
  r.y = c.x + c.y * a.y + c.z * b.y + c.w * (a.y * b.y);
  return r;
}
__device__ __forceinline__ float2 h2f2(h2 v) {
  return make_float2((float)v[0], (float)v[1]);
}
__device__ __forceinline__ float4 dec_cf(uint2 u) {
  h2 p0, p1;
  *(unsigned*)&p0 = u.x;
  *(unsigned*)&p1 = u.y;
  return make_float4((float)p0[0], (float)p0[1], (float)p1[0], (float)p1[1]);
}

// one conv_tree+orpool stage, global->global, feature-major h2.
// in [C][H][W][64], out [OC][PH][PW][64].
template <int C, int H, int W, int OC>
__device__ void conv_stage(const h2* __restrict__ in, h2* __restrict__ out,
                           const int* __restrict__ leaf,
                           const float4* __restrict__ coef, int gtid) {
  constexpr int PH = H / 2, PW = W / 2;
  constexpr int NJ = OC * PH * PW * 64;
  for (int j = gtid; j < NJ; j += GSZ) {
    int bp = j & 63;
    int t = j >> 6;
    int pw = t % PW; t /= PW;
    int ph = t % PH; t /= PH;
    int oc = t;

    int cc[8], di[8], dj[8];
#pragma unroll
    for (int l = 0; l < 8; ++l) {
      int k = leaf[oc * 8 + l];
      cc[l] = k / 9;
      int p = k - 9 * cc[l];
      di[l] = p / 3;
      dj[l] = p - 3 * di[l];
    }
    float4 c0 = coef[oc * 4 + 0];
    float4 c1 = coef[oc * 4 + 1];
    float4 c2 = coef[oc * 4 + 2];
    float4 c3 = coef[oc * 4 + 3];

    float2 best = make_float2(-1e30f, -1e30f);
#pragma unroll
    for (int py = 0; py < 2; ++py) {
#pragma unroll
      for (int px = 0; px < 2; ++px) {
        int i = 2 * ph + py, jx = 2 * pw + px;
        float2 lv[8];
#pragma unroll
        for (int l = 0; l < 8; ++l) {
          int ii = i + di[l] - 1, jj = jx + dj[l] - 1;
          float2 v = make_float2(0.f, 0.f);
          if ((unsigned)ii < (unsigned)H && (unsigned)jj < (unsigned)W)
            v = h2f2(in[((cc[l] * H + ii) * W + jj) * 64 + bp]);
          lv[l] = v;
        }
        float2 t0 = gate2(c0, lv[0], lv[1]);
        float2 t1 = gate2(c1, lv[2], lv[3]);
        float2 t2 = gate2(c2, lv[4], lv[5]);
        float2 t3 = gate2(c3, lv[6], lv[7]);
        float2 u0 = gate2(c1, t0, t1);
        float2 u1 = gate2(c2, t2, t3);
        float2 o = gate2(c3, u0, u1);
        best.x = fmaxf(best.x, o.x);
        best.y = fmaxf(best.y, o.y);
      }
    }
    h2 r; r[0] = (_Float16)best.x; r[1] = (_Float16)best.y;
    out[(oc * (PH * PW) + ph * PW + pw) * 64 + bp] = r;
  }
}

__global__ __launch_bounds__(1024) void coop(
    const float* __restrict__ x,
    const float* __restrict__ w1, const float* __restrict__ w2,
    const float* __restrict__ w3, const float* __restrict__ w4,
    const float* __restrict__ fw1, const float* __restrict__ fw2,
    const float* __restrict__ fw3,
    const int* __restrict__ l1, const int* __restrict__ l2,
    const int* __restrict__ l3, const int* __restrict__ l4,
    const int* __restrict__ ca1, const int* __restrict__ cb1,
    const int* __restrict__ ca2, const int* __restrict__ cb2,
    const int* __restrict__ ca3, const int* __restrict__ cb3,
    float* __restrict__ out, char* __restrict__ ws) {
  cg::grid_group grid = cg::this_grid();
  int tid = threadIdx.x;
  int gtid = blockIdx.x * 1024 + tid;

  // workspace carve-up (16B-aligned offsets)
  float4*         coefC  = (float4*)ws;                    // 6784*16   = 108,544
  unsigned short* midx16 = (unsigned short*)(ws + 108544); // 10240*8*2 = 163,840
  _Float16*       mcoefh = (_Float16*)(ws + 272384);       // 10240*28*2= 573,440
  h2*             xb     = (h2*)(ws + 845824);             // 9*1024*64 *4 = 2,359,296
  h2*             bufA   = (h2*)(ws + 3205120);            // 2,097,152
  h2*             bufB   = (h2*)(ws + 5302272);            // 2,097,152
  float2*         part   = (float2*)(ws + 7399424);        // 640*64*8  = 327,680

  // ---- P0: prep (78,464 jobs) + binarize (3*1024*64 = 196,608 jobs) ----
  for (int j = gtid; j < 78464 + 196608; j += GSZ) {
    if (j < 71680) {  // FC tree chase: o = j/7, slot s = j%7
      int o = j / 7;
      int s = j - o * 7;
      float4 c;
      if (s < 4) {
        int k = (s < 2) ? ca3[o] : cb3[o];
        int jj = (s & 1) ? cb2[k] : ca2[k];
        midx16[o * 8 + s * 2]     = (unsigned short)ca1[jj];
        midx16[o * 8 + s * 2 + 1] = (unsigned short)cb1[jj];
        c = softmax_coef(fw1 + jj * 16);
      } else if (s < 6) {
        int k = (s == 4) ? ca3[o] : cb3[o];
        c = softmax_coef(fw2 + k * 16);
      } else {
        c = softmax_coef(fw3 + o * 16);
      }
      _Float16* mc = mcoefh + o * 28 + s * 4;
      mc[0] = (_Float16)c.x; mc[1] = (_Float16)c.y;
      mc[2] = (_Float16)c.z; mc[3] = (_Float16)c.w;
    } else if (j < 78464) {  // conv gate coefs
      int gg = j - 71680;
      int base = gg;
      const float* w;
      if (gg < 128)       {             w = w1; }
      else if (gg < 640)  { gg -= 128;  w = w2; }
      else if (gg < 2688) { gg -= 640;  w = w3; }
      else                { gg -= 2688; w = w4; }
      coefC[base] = softmax_coef(w + ((gg >> 2) * 7 + (gg & 3)) * 16);
    } else {  // binarize: job = (c, pos, bp); 3 thresholds per job
      int jj = j - 78464;
      int bp = jj & 63;
      int pos = (jj >> 6) & 1023;
      int c = jj >> 16;
      float lo = x[(2 * bp) * 3072 + c * 1024 + pos];
      float hi = x[(2 * bp + 1) * 3072 + c * 1024 + pos];
#pragma unroll
      for (int th = 0; th < 3; ++th) {
        float thr = (float)(th + 1) * 0.25f;
        h2 v;
        v[0] = (_Float16)((lo > thr) ? 1.f : 0.f);
        v[1] = (_Float16)((hi > thr) ? 1.f : 0.f);
        xb[((th * 3 + c) * 1024 + pos) * 64 + bp] = v;
      }
    }
  }
  grid.sync();

  // ---- conv tower ----
  conv_stage<9, 32, 32, 32>(xb, bufA, l1, coefC, gtid);
  grid.sync();
  conv_stage<32, 16, 16, 128>(bufA, bufB, l2, coefC + 128, gtid);
  grid.sync();
  conv_stage<128, 8, 8, 512>(bufB, bufA, l3, coefC + 640, gtid);
  grid.sync();
  conv_stage<512, 4, 4, 1024>(bufA, bufB, l4, coefC + 2688, gtid);
  grid.sync();

  // ---- FC: 3 passes; block = 16 og x 64 bp; part[u][bp], u = p*256+blk ----
  __shared__ float2 red[16][64];
  {
    const uint4* mi = (const uint4*)midx16;
    const uint2* mc = (const uint2*)mcoefh;
    int og = tid >> 6, bp = tid & 63;
#pragma unroll
    for (int p = 0; p < 3; ++p) {
      int o = p * 4096 + blockIdx.x * 16 + og;
      float2 y = make_float2(0.f, 0.f);
      if (o < 10240) {
        uint4 I = mi[o];
        const uint2* cfp = mc + o * 7;
        float2 a0 = h2f2(bufB[(I.x & 0xffff) * 64 + bp]);
        float2 b0 = h2f2(bufB[(I.x >> 16) * 64 + bp]);
        float2 a1 = h2f2(bufB[(I.y & 0xffff) * 64 + bp]);
        float2 b1 = h2f2(bufB[(I.y >> 16) * 64 + bp]);
        float2 a2 = h2f2(bufB[(I.z & 0xffff) * 64 + bp]);
        float2 b2 = h2f2(bufB[(I.z >> 16) * 64 + bp]);
        float2 a3 = h2f2(bufB[(I.w & 0xffff) * 64 + bp]);
        float2 b3 = h2f2(bufB[(I.w >> 16) * 64 + bp]);
        float2 L0 = gate2(dec_cf(cfp[0]), a0, b0);
        float2 L1 = gate2(dec_cf(cfp[1]), a1, b1);
        float2 L2 = gate2(dec_cf(cfp[2]), a2, b2);
        float2 L3 = gate2(dec_cf(cfp[3]), a3, b3);
        float2 M0 = gate2(dec_cf(cfp[4]), L0, L1);
        float2 M1 = gate2(dec_cf(cfp[5]), L2, L3);
        y = gate2(dec_cf(cfp[6]), M0, M1);
      }
      red[og][bp] = y;
      __syncthreads();
#pragma unroll
      for (int s = 8; s > 0; s >>= 1) {
        if (og < s) {
          red[og][bp].x += red[og + s][bp].x;
          red[og][bp].y += red[og + s][bp].y;
        }
        __syncthreads();
      }
      int u = p * 256 + blockIdx.x;
      if (og == 0 && u < 640) part[u * 64 + bp] = red[0][bp];
      __syncthreads();
    }
  }
  grid.sync();

  // ---- final class reduce: out[b*10+cls] = 0.1 * sum_u part[cls*64+u][bp] ----
  if (gtid < 1280) {
    int cls = gtid % 10;
    int b = gtid / 10;
    int bp = b >> 1, sel = b & 1;
    float s = 0.f;
#pragma unroll
    for (int u = 0; u < 64; ++u) {
      float2 v = part[(cls * 64 + u) * 64 + bp];
      s += sel ? v.y : v.x;
    }
    out[b * 10 + cls] = s * 0.1f;
  }
}

extern "C" void kernel_launch(void* const* d_in, const int* in_sizes, int n_in,
                              void* d_out, int out_size, void* d_ws, size_t ws_size,
                              hipStream_t stream) {
  const float* x   = (const float*)d_in[0];
  const float* w1  = (const float*)d_in[1];
  const float* w2  = (const float*)d_in[2];
  const float* w3  = (const float*)d_in[3];
  const float* w4  = (const float*)d_in[4];
  const float* fw1 = (const float*)d_in[5];
  const float* fw2 = (const float*)d_in[6];
  const float* fw3 = (const float*)d_in[7];
  const int* l1  = (const int*)d_in[8];
  const int* l2  = (const int*)d_in[9];
  const int* l3  = (const int*)d_in[10];
  const int* l4  = (const int*)d_in[11];
  const int* ca1 = (const int*)d_in[12];
  const int* cb1 = (const int*)d_in[13];
  const int* ca2 = (const int*)d_in[14];
  const int* cb2 = (const int*)d_in[15];
  const int* ca3 = (const int*)d_in[16];
  const int* cb3 = (const int*)d_in[17];
  float* out = (float*)d_out;
  char* ws = (char*)d_ws;

  void* args[] = {&x, &w1, &w2, &w3, &w4, &fw1, &fw2, &fw3,
                  &l1, &l2, &l3, &l4, &ca1, &cb1, &ca2, &cb2, &ca3, &cb3,
                  &out, &ws};
  hipLaunchCooperativeKernel((void*)coop, dim3(256), dim3(1024), args, 0, stream);
}

// Round 9
// 161.344 us; speedup vs baseline: 1.8183x; 1.8183x over previous
//
#include <hip/hip_runtime.h>
#include <math.h>

// ---------------------------------------------------------------------------
// ConvLogicNetCIFAR forward. R9: cooperative kernel, 256 blocks x 1024 thr =
// 128 groups x 2 blocks. Group g owns batch elem g; activations in GLOBAL
// (L2) [g][feat] fp16; the pair splits output channels per conv stage and
// syncs via agent-scope release/acquire flag spin (grid.sync measured ~40us
// each in R8 -- pair sync is ~1-2us). Pairing b <-> b^128 keeps both blocks
// on one XCD under %8 round-robin (heuristic only; correctness from agent
// scope). Binarize fused into stage1 (reads raw x). FC classes split 5/5.
// Prep (softmax coefs + FC tree chase + flag zeroing) is a separate tiny
// dispatch: per-block-redundant FC prep would re-read ~576MB of fw weights.
// Gate: c0 + c1*a + c2*b + c3*(a*b), c = softmax(w_row)@COEF.
// Conv tree quirk: off=2^lvl-1 -> level0 rows0..3, level1 rows1..2, level2 row3.
// ---------------------------------------------------------------------------

typedef _Float16 h16;
typedef _Float16 h2v __attribute__((ext_vector_type(2)));

#define NTHR 1024

__constant__ float c_coef_tbl[16][4] = {
    {0, 0, 0, 0}, {0, 0, 0, 1}, {0, 1, 0, -1}, {0, 1, 0, 0},
    {0, 0, 1, -1}, {0, 0, 1, 0}, {0, 1, 1, -2}, {0, 1, 1, -1},
    {1, -1, -1, 1}, {1, -1, -1, 2}, {1, 0, -1, 0}, {1, 0, -1, 1},
    {1, -1, 0, 0}, {1, -1, 0, 1}, {1, 0, 0, -1}, {1, 0, 0, 0}};

__device__ __forceinline__ float4 softmax_coef(const float* __restrict__ wr) {
  float m = -1e30f;
#pragma unroll
  for (int k = 0; k < 16; ++k) m = fmaxf(m, wr[k]);
  float e[16], s = 0.f;
#pragma unroll
  for (int k = 0; k < 16; ++k) { e[k] = __expf(wr[k] - m); s += e[k]; }
  float inv = 1.f / s;
  float c0 = 0.f, c1 = 0.f, c2 = 0.f, c3 = 0.f;
#pragma unroll
  for (int k = 0; k < 16; ++k) {
    c0 += e[k] * c_coef_tbl[k][0];
    c1 += e[k] * c_coef_tbl[k][1];
    c2 += e[k] * c_coef_tbl[k][2];
    c3 += e[k] * c_coef_tbl[k][3];
  }
  return make_float4(c0 * inv, c1 * inv, c2 * inv, c3 * inv);
}

__device__ __forceinline__ float gate_eval(float4 c, float a, float b) {
  return c.x + c.y * a + c.z * b + c.w * (a * b);
}
__device__ __forceinline__ float4 dec_cf(uint2 u) {
  h2v p0, p1;
  *(unsigned*)&p0 = u.x;
  *(unsigned*)&p1 = u.y;
  return make_float4((float)p0[0], (float)p0[1], (float)p1[0], (float)p1[1]);
}

// prep: g<71680 FC tree (o=g/7, s=g%7 -> fp16 coefs mcoefh[o*28+s*4], u16
// midx); [71680,78464) conv gate coefs float4; g<256 zeroes the sync flags.
__global__ void prep_all(const float* __restrict__ w1, const float* __restrict__ w2,
                         const float* __restrict__ w3, const float* __restrict__ w4,
                         const float* __restrict__ fw1, const float* __restrict__ fw2,
                         const float* __restrict__ fw3,
                         const int* __restrict__ ca1, const int* __restrict__ cb1,
                         const int* __restrict__ ca2, const int* __restrict__ cb2,
                         const int* __restrict__ ca3, const int* __restrict__ cb3,
                         float4* __restrict__ coefC,
                         unsigned short* __restrict__ midx16,
                         _Float16* __restrict__ mcoefh,
                         unsigned int* __restrict__ flags) {
  int g = blockIdx.x * blockDim.x + threadIdx.x;
  if (g < 256) flags[g] = 0u;
  if (g < 71680) {
    int o = g / 7;
    int s = g - o * 7;
    float4 c;
    if (s < 4) {
      int k = (s < 2) ? ca3[o] : cb3[o];
      int j = (s & 1) ? cb2[k] : ca2[k];
      midx16[o * 8 + s * 2]     = (unsigned short)ca1[j];
      midx16[o * 8 + s * 2 + 1] = (unsigned short)cb1[j];
      c = softmax_coef(fw1 + j * 16);
    } else if (s < 6) {
      int k = (s == 4) ? ca3[o] : cb3[o];
      c = softmax_coef(fw2 + k * 16);
    } else {
      c = softmax_coef(fw3 + o * 16);
    }
    _Float16* mc = mcoefh + o * 28 + s * 4;
    mc[0] = (_Float16)c.x; mc[1] = (_Float16)c.y;
    mc[2] = (_Float16)c.z; mc[3] = (_Float16)c.w;
  } else if (g < 78464) {
    int gg = g - 71680;
    int base = gg;
    const float* w;
    if (gg < 128)       {             w = w1; }
    else if (gg < 640)  { gg -= 128;  w = w2; }
    else if (gg < 2688) { gg -= 640;  w = w3; }
    else                { gg -= 2688; w = w4; }
    coefC[base] = softmax_coef(w + ((gg >> 2) * 7 + (gg & 3)) * 16);
  }
}

// pair barrier: release my flag=s, spin until partner flag >= s.
__device__ __forceinline__ void psync(unsigned int* flags, int me, int pa,
                                      unsigned int s, int tid) {
  __syncthreads();
  if (tid == 0) {
    __threadfence();  // make this block's global writes agent-visible
    __hip_atomic_store(&flags[me], s, __ATOMIC_RELEASE, __HIP_MEMORY_SCOPE_AGENT);
    while (__hip_atomic_load(&flags[pa], __ATOMIC_ACQUIRE,
                             __HIP_MEMORY_SCOPE_AGENT) < s) {
      __builtin_amdgcn_s_sleep(2);
    }
  }
  __syncthreads();
}

// one conv_tree+orpool stage for this block's half of the output channels.
// in: [C][H][W] fp16 (batch-local base); out: [OC][PH][PW] fp16.
// BIN: read raw x fp32 (xsrc, [3][32][32]) and binarize inline
// (leaf channel cc -> base chan cc%3, threshold (cc/3+1)*0.25).
template <int C, int H, int W, int OC, bool BIN>
__device__ void stage(const h16* __restrict__ in, const float* __restrict__ xsrc,
                      h16* __restrict__ outp, const int* __restrict__ leaf,
                      const float4* __restrict__ coef, int role, int tid) {
  constexpr int PH = H / 2, PW = W / 2, HW = H * W;
  constexpr int NPOS = PH * PW;
  constexpr int NJ = (OC / 2) * NPOS;
  constexpr int ITER = NJ / NTHR;
  int ocBase = role * (OC / 2);
#pragma unroll 2
  for (int it = 0; it < ITER; ++it) {
    int job = it * NTHR + tid;
    int pos = job % NPOS;
    int oc = ocBase + job / NPOS;
    int pw = pos % PW, ph = pos / PW;

    int cc[8], di[8], dj[8];
#pragma unroll
    for (int l = 0; l < 8; ++l) {
      int k = leaf[oc * 8 + l];
      cc[l] = k / 9;
      int p = k - 9 * cc[l];
      di[l] = p / 3;
      dj[l] = p - 3 * di[l];
    }
    float4 c0 = coef[oc * 4 + 0];
    float4 c1 = coef[oc * 4 + 1];
    float4 c2 = coef[oc * 4 + 2];
    float4 c3 = coef[oc * 4 + 3];

    float best = -1e30f;
#pragma unroll
    for (int py = 0; py < 2; ++py) {
#pragma unroll
      for (int px = 0; px < 2; ++px) {
        int i = 2 * ph + py, j = 2 * pw + px;
        float lv[8];
#pragma unroll
        for (int l = 0; l < 8; ++l) {
          int ii = i + di[l] - 1, jj = j + dj[l] - 1;
          float v = 0.f;
          if ((unsigned)ii < (unsigned)H && (unsigned)jj < (unsigned)W) {
            if (BIN) {
              int bc = cc[l] % 3;
              float thr = (float)(cc[l] / 3 + 1) * 0.25f;
              v = (xsrc[bc * 1024 + ii * 32 + jj] > thr) ? 1.f : 0.f;
            } else {
              v = (float)in[cc[l] * HW + ii * W + jj];
            }
          }
          lv[l] = v;
        }
        float t0 = gate_eval(c0, lv[0], lv[1]);
        float t1 = gate_eval(c1, lv[2], lv[3]);
        float t2 = gate_eval(c2, lv[4], lv[5]);
        float t3 = gate_eval(c3, lv[6], lv[7]);
        float u0 = gate_eval(c1, t0, t1);
        float u1 = gate_eval(c2, t2, t3);
        best = fmaxf(best, gate_eval(c3, u0, u1));
      }
    }
    outp[oc * NPOS + pos] = (h16)best;
  }
}

__global__ __launch_bounds__(1024) void coop(
    const float* __restrict__ x, const float4* __restrict__ coefC,
    const int* __restrict__ l1, const int* __restrict__ l2,
    const int* __restrict__ l3, const int* __restrict__ l4,
    const unsigned short* __restrict__ midx16,
    const _Float16* __restrict__ mcoefh,
    h16* __restrict__ s1, h16* __restrict__ s2,
    h16* __restrict__ s3, h16* __restrict__ s4,
    unsigned int* __restrict__ flags, float* __restrict__ out) {
  __shared__ float red[16];
  int tid = threadIdx.x;
  int me = blockIdx.x;
  int g = me & 127;          // group = batch element
  int role = me >> 7;        // 0 / 1
  int pa = me ^ 128;         // partner (same XCD under %8 round-robin)

  const float* xg = x + g * 3072;
  h16* b1 = s1 + g * 8192;   // 32*16*16
  h16* b2 = s2 + g * 8192;   // 128*8*8
  h16* b3 = s3 + g * 8192;   // 512*4*4
  h16* b4 = s4 + g * 4096;   // 1024*2*2

  stage<9, 32, 32, 32, true>(nullptr, xg, b1, l1, coefC, role, tid);
  psync(flags, me, pa, 1, tid);
  stage<32, 16, 16, 128, false>(b1, nullptr, b2, l2, coefC + 128, role, tid);
  psync(flags, me, pa, 2, tid);
  stage<128, 8, 8, 512, false>(b2, nullptr, b3, l3, coefC + 640, role, tid);
  psync(flags, me, pa, 3, tid);
  stage<512, 4, 4, 1024, false>(b3, nullptr, b4, l4, coefC + 2688, role, tid);
  psync(flags, me, pa, 4, tid);

  // FC: this block covers classes role*5 .. role*5+4; o = cls*1024 + tid.
  const uint4* mi = (const uint4*)midx16;
  const uint2* mc = (const uint2*)mcoefh;
#pragma unroll
  for (int k = 0; k < 5; ++k) {
    int cls = role * 5 + k;
    int o = cls * 1024 + tid;
    uint4 I = mi[o];
    const uint2* cfp = mc + o * 7;
    float L0 = gate_eval(dec_cf(cfp[0]), (float)b4[I.x & 0xffff], (float)b4[I.x >> 16]);
    float L1 = gate_eval(dec_cf(cfp[1]), (float)b4[I.y & 0xffff], (float)b4[I.y >> 16]);
    float L2 = gate_eval(dec_cf(cfp[2]), (float)b4[I.z & 0xffff], (float)b4[I.z >> 16]);
    float L3 = gate_eval(dec_cf(cfp[3]), (float)b4[I.w & 0xffff], (float)b4[I.w >> 16]);
    float M0 = gate_eval(dec_cf(cfp[4]), L0, L1);
    float M1 = gate_eval(dec_cf(cfp[5]), L2, L3);
    float y = gate_eval(dec_cf(cfp[6]), M0, M1);
#pragma unroll
    for (int m = 32; m > 0; m >>= 1) y += __shfl_xor(y, m, 64);
    if ((tid & 63) == 0) red[tid >> 6] = y;
    __syncthreads();
    if (tid == 0) {
      float s = 0.f;
#pragma unroll
      for (int w = 0; w < 16; ++w) s += red[w];
      out[g * 10 + cls] = s * 0.1f;
    }
    __syncthreads();
  }
}

extern "C" void kernel_launch(void* const* d_in, const int* in_sizes, int n_in,
                              void* d_out, int out_size, void* d_ws, size_t ws_size,
                              hipStream_t stream) {
  const float* x   = (const float*)d_in[0];
  const float* w1  = (const float*)d_in[1];
  const float* w2  = (const float*)d_in[2];
  const float* w3  = (const float*)d_in[3];
  const float* w4  = (const float*)d_in[4];
  const float* fw1 = (const float*)d_in[5];
  const float* fw2 = (const float*)d_in[6];
  const float* fw3 = (const float*)d_in[7];
  const int* l1  = (const int*)d_in[8];
  const int* l2  = (const int*)d_in[9];
  const int* l3  = (const int*)d_in[10];
  const int* l4  = (const int*)d_in[11];
  const int* ca1 = (const int*)d_in[12];
  const int* cb1 = (const int*)d_in[13];
  const int* ca2 = (const int*)d_in[14];
  const int* cb2 = (const int*)d_in[15];
  const int* ca3 = (const int*)d_in[16];
  const int* cb3 = (const int*)d_in[17];
  float* out = (float*)d_out;

  char* ws = (char*)d_ws;
  float4*         coefC  = (float4*)ws;                       // 108,544 B
  unsigned short* midx16 = (unsigned short*)(ws + 108544);    // 163,840 B
  _Float16*       mcoefh = (_Float16*)(ws + 272384);          // 573,440 B
  unsigned int*   flags  = (unsigned int*)(ws + 845824);      // 1,024 B
  h16*            s1b    = (h16*)(ws + 846848);               // 2,097,152 B
  h16*            s2b    = (h16*)(ws + 846848 + 2097152);     // 2,097,152 B
  h16*            s3b    = (h16*)(ws + 846848 + 2 * 2097152); // 2,097,152 B
  h16*            s4b    = (h16*)(ws + 846848 + 3 * 2097152); // 1,048,576 B

  prep_all<<<307, 256, 0, stream>>>(w1, w2, w3, w4, fw1, fw2, fw3,
                                    ca1, cb1, ca2, cb2, ca3, cb3,
                                    coefC, midx16, mcoefh, flags);

  void* args[] = {&x, &coefC, &l1, &l2, &l3, &l4, &midx16, &mcoefh,
                  &s1b, &s2b, &s3b, &s4b, &flags, &out};
  hipLaunchCooperativeKernel((void*)coop, dim3(256), dim3(1024), args, 0, stream);
}